// Round 3
// baseline (18938.771 us; speedup 1.0000x reference)
//
#include <hip/hip_runtime.h>
#include <hip/hip_bf16.h>
#include <hip/hip_fp16.h>
#include <math.h>

// ---------------------------------------------------------------------------
// Seq2Seq (bi-LSTM encoder x2 + fixed-state decoder), B=64 T=1024 H=256.
// THIS ROUND: batch-parallel restructure. WG = (dir, batch) for encoder,
// WG = batch for decoder. h/c live INSIDE the WG -> the 1024-step recurrent
// loops have NO global barriers and NO coherent-point traffic at all.
// Weights per step: row t in VGPRs (128) + 256 rows swizzled in LDS (E0)
// + remainder streamed from L2 (fp16 copies prepared once in ws).
// E1 input-dot (y0 @ Wih1, h-independent) batched in 16-step windows
// (G fp32 in LDS; Wih1 bf16 streamed once/window, cvt amortized 16x).
// Decoder: per-batch WG, exact per-b fixed-point exit; dWih1 -> fp16 into
// dead y0 space. R-const phase kept verbatim from round 2.
// ---------------------------------------------------------------------------

#define NWG 256
#define THR 512
#define U0S 132      // R-phase A-tile stride in uints

// ws layout (float offsets); first 2048 floats = barrier counters (8 KB)
#define RA_F   2048                 // fp16 stream region A (65536 f = 16384 uint4)
#define ECL0   (RA_F + 65536)       // enc l0 final c (fp32): [dir*16384 + b*256 + k]
#define EHL1   (ECL0 + 32768)      // enc l1 final h (packed fp16): uint[dir*8192 + b*128 + wl]
#define ECL1   (EHL1 + 32768)      // enc l1 final c (fp32)
#define ROF    (ECL1 + 32768)      // decoder recurrent consts R (fp32): [m*65536 + b*1024 + r]
#define RB_F   (ROF + 262144)      // fp16 stream region B (81920 f; 16384 uint4 used)
#define Y0OF   524288              // packed fp16 y0: uint[t*16384 + b*256 + dir*128 + wl]
#define WS_REQ_BYTES ((size_t)(Y0OF + 16777216) * 4)   // ~69 MB (unchanged)

struct SeqParams {
  const void *x, *eWih0, *eWhh0, *eB0, *eWih1, *eWhh1, *eB1;
  const void *dWih0, *dWhh0, *dB0, *dWih1, *dWhh1, *dB1, *fcW, *fcb;
  void* out;
  float* ws;
  unsigned* ctrs;
};

typedef _Float16 hlf2 __attribute__((ext_vector_type(2)));

__device__ __forceinline__ float bf2f(unsigned short u) {
  return __uint_as_float(((unsigned)u) << 16);
}
__device__ __forceinline__ float hf2f(unsigned short u) {
  __half_raw r; r.x = u; return __half2float(__half(r));
}
__device__ __forceinline__ unsigned short f2h_u(float f) {
  __half h = __float2half(f);
  return *reinterpret_cast<unsigned short*>(&h);
}
__device__ __forceinline__ float sigm(float v) { return 1.0f / (1.0f + expf(-v)); }

#if __has_builtin(__builtin_amdgcn_fdot2)
__device__ __forceinline__ float fdot2(hlf2 a, hlf2 b, float c) {
  return __builtin_amdgcn_fdot2(a, b, c, false);
}
#else
__device__ __forceinline__ float fdot2(hlf2 a, hlf2 b, float c) {
  return c + (float)a[0] * (float)b[0] + (float)a[1] * (float)b[1];
}
#endif

__device__ __forceinline__ float ldin(const void* p_, size_t i, int bf) {
  return bf ? bf2f(((const unsigned short*)p_)[i]) : ((const float*)p_)[i];
}
__device__ __forceinline__ void stout(void* o, size_t i, float v, int bf) {
  if (bf) ((__hip_bfloat16*)o)[i] = __float2bfloat16(v);
  else    ((float*)o)[i] = v;
}

// probe storage dtype from x (N(0,1) samples)
__device__ __forceinline__ int detect_bf16(const void* xp) {
  const unsigned* u = (const unsigned*)xp;
  int votes = 0;
#pragma unroll 8
  for (int i = 0; i < 64; ++i) {
    unsigned e = (u[i] >> 7) & 0xFF;
    votes += (e >= 108 && e <= 131) ? 1 : 0;
  }
  return votes >= 32;
}

// ---- full barrier (fenced release/acquire; phase transitions only) ---------
__device__ __forceinline__ void gbar(unsigned* ctrs, unsigned gen) {
  __syncthreads();
  if (threadIdx.x == 0) {
    __hip_atomic_fetch_add(&ctrs[(blockIdx.x & 31) * 32], 1u,
                           __ATOMIC_RELEASE, __HIP_MEMORY_SCOPE_AGENT);
  }
  if (threadIdx.x < 32) {
    while (__hip_atomic_load(&ctrs[threadIdx.x * 32], __ATOMIC_RELAXED,
                             __HIP_MEMORY_SCOPE_AGENT) < gen * 8u) {
      __builtin_amdgcn_s_sleep(1);
    }
    (void)__hip_atomic_load(&ctrs[threadIdx.x * 32], __ATOMIC_ACQUIRE,
                            __HIP_MEMORY_SCOPE_AGENT);
  }
  __syncthreads();
}

// ---- helpers ---------------------------------------------------------------
// 8-elem chunk of a weight row (bf16 or fp32 global) -> packed fp16 uint4
__device__ __forceinline__ uint4 ldw8(const void* src, size_t off, int bf) {
  union { __half h[8]; uint4 u; } r;
  if (bf) {
    const unsigned short* s = (const unsigned short*)src + off;
    ushort4 a = *reinterpret_cast<const ushort4*>(s);
    ushort4 b = *reinterpret_cast<const ushort4*>(s + 4);
    r.h[0] = __float2half(bf2f(a.x)); r.h[1] = __float2half(bf2f(a.y));
    r.h[2] = __float2half(bf2f(a.z)); r.h[3] = __float2half(bf2f(a.w));
    r.h[4] = __float2half(bf2f(b.x)); r.h[5] = __float2half(bf2f(b.y));
    r.h[6] = __float2half(bf2f(b.z)); r.h[7] = __float2half(bf2f(b.w));
  } else {
    const float* s = (const float*)src + off;
    float4 a = *reinterpret_cast<const float4*>(s);
    float4 b = *reinterpret_cast<const float4*>(s + 4);
    r.h[0] = __float2half(a.x); r.h[1] = __float2half(a.y);
    r.h[2] = __float2half(a.z); r.h[3] = __float2half(a.w);
    r.h[4] = __float2half(b.x); r.h[5] = __float2half(b.y);
    r.h[6] = __float2half(b.z); r.h[7] = __float2half(b.w);
  }
  return r.u;
}

__device__ __forceinline__ void dot2acc(float4& a, const uint4& hv, const uint4& wv) {
  const hlf2* hp = reinterpret_cast<const hlf2*>(&hv);
  const hlf2* wp = reinterpret_cast<const hlf2*>(&wv);
  a.x = fdot2(hp[0], wp[0], a.x);
  a.y = fdot2(hp[1], wp[1], a.y);
  a.z = fdot2(hp[2], wp[2], a.z);
  a.w = fdot2(hp[3], wp[3], a.w);
}

// ---- R-phase helpers (verbatim from round 2) -------------------------------
__device__ __forceinline__ void stage_u128(unsigned* AH, const unsigned* src,
                                           int ustr, int uoff) {
  const int t = threadIdx.x;
#pragma unroll
  for (int i = 0; i < 4; ++i) {
    int idx = t + i * THR;
    int r = idx >> 5, c4 = (idx & 31) << 2;
    uint4 v = *reinterpret_cast<const uint4*>(src + (size_t)r * ustr + uoff + c4);
    *reinterpret_cast<uint4*>(AH + r * U0S + c4) = v;
  }
}
__device__ __forceinline__ void load_w16_rows(uint4 (&wr)[2][4], const void* src,
                                              int rowbase, int bf) {
  const int t = threadIdx.x, kc = t >> 6, rt = t & 3;
#pragma unroll
  for (int j = 0; j < 2; ++j) {
    size_t rb = (size_t)(rowbase + rt * 2 + j) * 256 + kc * 32;
#pragma unroll
    for (int d = 0; d < 4; ++d) wr[j][d] = ldw8(src, rb + d * 8, bf);
  }
}
__device__ __forceinline__ void dot2_t4(float4* acc, const unsigned* A,
                                        const uint4 (&wr)[2][4]) {
  const int t = threadIdx.x;
  const int kc = t >> 6, bt = (t & 63) >> 2;
#pragma unroll
  for (int d = 0; d < 4; ++d) {
    const int k = kc * 16 + d * 4;
    uint4 h0 = *reinterpret_cast<const uint4*>(A + (bt +  0) * U0S + k);
    uint4 h1 = *reinterpret_cast<const uint4*>(A + (bt + 16) * U0S + k);
    uint4 h2 = *reinterpret_cast<const uint4*>(A + (bt + 32) * U0S + k);
    uint4 h3 = *reinterpret_cast<const uint4*>(A + (bt + 48) * U0S + k);
    dot2acc(acc[0], h0, wr[0][d]); dot2acc(acc[1], h0, wr[1][d]);
    dot2acc(acc[2], h1, wr[0][d]); dot2acc(acc[3], h1, wr[1][d]);
    dot2acc(acc[4], h2, wr[0][d]); dot2acc(acc[5], h2, wr[1][d]);
    dot2acc(acc[6], h3, wr[0][d]); dot2acc(acc[7], h3, wr[1][d]);
  }
}
__device__ __forceinline__ void reduce_R(const float4* acc, float* part, float* dst,
                                         const void* bsrc, int rowbase, int bf) {
  const int t = threadIdx.x;
  const int kc = t >> 6, tile = t & 63;
#pragma unroll
  for (int e = 0; e < 8; ++e) {
    const float4 a = acc[e];
    part[e * 512 + kc * 64 + tile] = (a.x + a.y) + (a.z + a.w);
  }
  __syncthreads();
  {
    const int r = t >> 6, b = t & 63;
    const int tl = (b & 15) * 4 + (r >> 1);
    const float* pp = part + ((b >> 4) * 2 + (r & 1)) * 512 + tl;
    float v = ((pp[0] + pp[64]) + (pp[128] + pp[192])) +
              ((pp[256] + pp[320]) + (pp[384] + pp[448]));
    dst[(size_t)b * 1024 + rowbase + r] = v + ldin(bsrc, rowbase + r, bf);
  }
  __syncthreads();
}

// ---------------------------------------------------------------------------
__global__ void __launch_bounds__(THR, 2) seq2seq_kernel(SeqParams p) {
  // smem: [0,4096) GF f[1024] | [4096,4608) H16 u[128] | [4608,12800) PRE f[2048]
  //       [12800,12864) YL | [12864,...) union:
  //         E0: Wc uint4[8192] (131072 B)
  //         E1: YW uint[4096] (16 KB) + GW float[16*1024] (64 KB)
  //         R : AH0 uint[8448] (33792 B) + part float[4096] (16 KB)
  //         dec: R0L f[2048] | WI0L f[2048] | C0L f[512] | ZV uint[128]
  __shared__ __align__(16) char smem[143936];
  float* GF = (float*)smem;
  unsigned* H16 = (unsigned*)(smem + 4096);
  float* PRE = (float*)(smem + 4608);
  float* YL = (float*)(smem + 12800);
  char* UN = smem + 12864;

  const int w = blockIdx.x;
  const int t = threadIdx.x;
  float* ws = p.ws;
  unsigned* ctrs = p.ctrs;
  unsigned* y0w = (unsigned*)(ws + Y0OF);
  uint4* RAu4 = (uint4*)(ws + RA_F);
  uint4* RBu4 = (uint4*)(ws + RB_F);
  unsigned* EHL1u = (unsigned*)(ws + EHL1);
  unsigned genF = 0;
  const int bfm = detect_bf16(p.x);
  const int enc_act = (w < 128);
  const int d = (w >> 6) & 1, b = w & 63;

  uint4 wreg[32];   // fp16 weight row t (K=256) for E0/E1 recurrent dots

  // ============================ prep + E0 prep =============================
  {
    if (t < 64) {   // E0 stream rows [768,1024) both dirs -> RA (16384 uint4)
      int idx = w * 64 + t;
      int dd = idx >> 13, rem = idx & 8191;
      int row = 768 + (rem >> 5), kc = rem & 31;
      RAu4[idx] = ldw8(p.eWhh0, (size_t)dd * 262144 + (size_t)row * 256 + kc * 8, bfm);
    }
    if (enc_act) {
      uint4* Wcu4 = (uint4*)UN;     // rows [512,768) of dir d, XOR-swizzled
#pragma unroll
      for (int i = 0; i < 16; ++i) {
        int u = t + i * THR;        // 0..8191
        int row = u >> 5, kc = u & 31;
        Wcu4[row * 32 + (kc ^ (row & 7))] =
            ldw8(p.eWhh0, (size_t)d * 262144 + (size_t)(512 + row) * 256 + kc * 8, bfm);
      }
      if (t < 256) {
#pragma unroll
        for (int g = 0; g < 4; ++g) {
          PRE[g * 256 + t]        = ldin(p.eB0,   d * 1024 + g * 256 + t, bfm);
          PRE[1024 + g * 256 + t] = ldin(p.eWih0, d * 1024 + g * 256 + t, bfm);
        }
      }
      if (t < 128) H16[t] = 0u;
#pragma unroll
      for (int kc = 0; kc < 32; ++kc)
        wreg[kc] = ldw8(p.eWhh0, (size_t)d * 262144 + (size_t)t * 256 + kc * 8, bfm);
    }
  }
  gbar(ctrs, ++genF);   // RA conversions visible; own-WG LDS synced

  // ====================== E0: 1024 steps, NO global sync ===================
  if (enc_act) {
    float cc = 0.f;     // c for col t (threads t<256)
    const uint4* Wcu4 = (const uint4*)UN;
    const uint4* strp = RAu4 + d * 8192 + (size_t)(t >= 256 ? t - 256 : 0) * 32;
    for (int st = 0; st < 1024; ++st) {
      const int tt = d ? (1023 - st) : st;
      float xv = (t < 256) ? ldin(p.x, (size_t)b * 1024 + tt, bfm) : 0.f;
      float4 a0 = {0.f, 0.f, 0.f, 0.f}, a1 = {0.f, 0.f, 0.f, 0.f};
      if (t < 256) {
        const uint4* wc = Wcu4 + t * 32;
#pragma unroll
        for (int kc = 0; kc < 32; ++kc) {
          uint4 hv = *(const uint4*)(H16 + kc * 4);
          dot2acc(a0, hv, wreg[kc]);
          dot2acc(a1, hv, wc[kc ^ (t & 7)]);
        }
      } else {
#pragma unroll
        for (int kc = 0; kc < 32; ++kc) {
          uint4 hv = *(const uint4*)(H16 + kc * 4);
          dot2acc(a0, hv, wreg[kc]);
          dot2acc(a1, hv, strp[kc]);
        }
      }
      GF[t]       = (a0.x + a0.y) + (a0.z + a0.w);
      GF[t + 512] = (a1.x + a1.y) + (a1.z + a1.w);
      __syncthreads();
      if (t < 256) {
        float gi = GF[t]       + PRE[t]       + xv * PRE[1024 + t];
        float gf = GF[256 + t] + PRE[256 + t] + xv * PRE[1280 + t];
        float gg = GF[512 + t] + PRE[512 + t] + xv * PRE[1536 + t];
        float go = GF[768 + t] + PRE[768 + t] + xv * PRE[1792 + t];
        float cn = sigm(gf) * cc + sigm(gi) * tanhf(gg);
        float hn = sigm(go) * tanhf(cn);
        cc = cn;
        ((unsigned short*)H16)[t] = f2h_u(hn);
        if (st == 1023) ws[ECL0 + d * 16384 + b * 256 + t] = cn;
      }
      __syncthreads();
      if (t < 128) y0w[(size_t)tt * 16384 + (size_t)b * 256 + d * 128 + t] = H16[t];
    }
  }
  gbar(ctrs, ++genF);   // y0 / ECL0 visible

  // ============================ E1 prep ====================================
  {
    if (t < 128) {      // E1 stream rows [512,1024), dir0->RA dir1->RB
      int idx = w * 128 + t;
      int dd = idx >> 14, rem = idx & 16383;
      int row = 512 + (rem >> 5), kc = rem & 31;
      uint4 v = ldw8(p.eWhh1, (size_t)dd * 262144 + (size_t)row * 256 + kc * 8, bfm);
      if (dd == 0) RAu4[rem] = v; else RBu4[rem] = v;
    }
    if (enc_act) {
      if (t < 256) {
#pragma unroll
        for (int g = 0; g < 4; ++g)
          PRE[g * 256 + t] = ldin(p.eB1, d * 1024 + g * 256 + t, bfm);
      }
      if (t < 128) H16[t] = 0u;
#pragma unroll
      for (int kc = 0; kc < 32; ++kc)
        wreg[kc] = ldw8(p.eWhh1, (size_t)d * 262144 + (size_t)t * 256 + kc * 8, bfm);
    }
  }
  gbar(ctrs, ++genF);

  // ====================== E1: 1024 steps, NO global sync ===================
  if (enc_act) {
    float cc = 0.f;
    unsigned* YW = (unsigned*)UN;                    // [16][256] packed y0
    float* GW = (float*)(UN + 16384);                // [16][1024] fp32 G
    const uint4* strp = (d == 0 ? RAu4 : RBu4) + (size_t)t * 32;
    const size_t r0off = (size_t)d * 524288 + (size_t)t * 512;   // Wih1 row t
    for (int st = 0; st < 1024; ++st) {
      if ((st & 15) == 0) {
        // ---- build y0 window (16 steps) ----
#pragma unroll
        for (int q = 0; q < 2; ++q) {
          int u = t + q * THR;          // 0..1023 uint4s
          int row = u >> 6, c4 = (u & 63) << 2;
          int tw = d ? (1023 - st - row) : (st + row);
          *(uint4*)(YW + row * 256 + c4) =
              *(const uint4*)(y0w + (size_t)tw * 16384 + (size_t)b * 256 + c4);
        }
        __syncthreads();
        // ---- window GEMM: G[w16][rows t, t+512] (fp32) ----
        float ac0[16], ac1[16];
#pragma unroll
        for (int i = 0; i < 16; ++i) { ac0[i] = 0.f; ac1[i] = 0.f; }
        for (int kc = 0; kc < 64; ++kc) {
          uint4 w0 = ldw8(p.eWih1, r0off + kc * 8, bfm);
          uint4 w1 = ldw8(p.eWih1, r0off + 262144 + kc * 8, bfm);
          const unsigned* yb = YW + kc * 4;
#pragma unroll
          for (int w16 = 0; w16 < 16; ++w16) {
            uint4 yv = *(const uint4*)(yb + w16 * 256);
            const hlf2* yp = (const hlf2*)&yv;
            const hlf2* w0p = (const hlf2*)&w0;
            const hlf2* w1p = (const hlf2*)&w1;
            float s0 = ac0[w16], s1 = ac1[w16];
            s0 = fdot2(yp[0], w0p[0], s0); s0 = fdot2(yp[1], w0p[1], s0);
            s0 = fdot2(yp[2], w0p[2], s0); s0 = fdot2(yp[3], w0p[3], s0);
            s1 = fdot2(yp[0], w1p[0], s1); s1 = fdot2(yp[1], w1p[1], s1);
            s1 = fdot2(yp[2], w1p[2], s1); s1 = fdot2(yp[3], w1p[3], s1);
            ac0[w16] = s0; ac1[w16] = s1;
          }
        }
#pragma unroll
        for (int w16 = 0; w16 < 16; ++w16) {
          GW[w16 * 1024 + t]       = ac0[w16];
          GW[w16 * 1024 + t + 512] = ac1[w16];
        }
      }
      // ---- recurrent dot (K=256) ----
      float4 a0 = {0.f, 0.f, 0.f, 0.f}, a1 = {0.f, 0.f, 0.f, 0.f};
#pragma unroll
      for (int kc = 0; kc < 32; ++kc) {
        uint4 hv = *(const uint4*)(H16 + kc * 4);
        dot2acc(a0, hv, wreg[kc]);
        dot2acc(a1, hv, strp[kc]);
      }
      GF[t]       = (a0.x + a0.y) + (a0.z + a0.w);
      GF[t + 512] = (a1.x + a1.y) + (a1.z + a1.w);
      __syncthreads();   // covers GW writes and GF writes
      if (t < 256) {
        const int sl = (st & 15) * 1024;
        float gi = GF[t]       + PRE[t]       + GW[sl + t];
        float gf = GF[256 + t] + PRE[256 + t] + GW[sl + 256 + t];
        float gg = GF[512 + t] + PRE[512 + t] + GW[sl + 512 + t];
        float go = GF[768 + t] + PRE[768 + t] + GW[sl + 768 + t];
        float cn = sigm(gf) * cc + sigm(gi) * tanhf(gg);
        float hn = sigm(go) * tanhf(cn);
        cc = cn;
        ((unsigned short*)H16)[t] = f2h_u(hn);
        if (st == 1023) ws[ECL1 + d * 16384 + b * 256 + t] = cn;
      }
      __syncthreads();
      if (st == 1023 && t < 128) EHL1u[d * 8192 + b * 128 + t] = H16[t];
    }
  }
  gbar(ctrs, ++genF);   // EHL1/ECL1 visible

  // ===================== decoder recurrent consts R (round-2 code) =========
  {
    unsigned* AH0 = (unsigned*)UN;
    float* part = (float*)(UN + 33792);
    const int m = w >> 6, wl6 = w & 63;
    const void* whh;
    if (bfm) whh = (m < 2) ? (const void*)((const unsigned short*)p.dWhh0 + (size_t)m * 262144)
                           : (const void*)((const unsigned short*)p.dWhh1 + (size_t)(m - 2) * 262144);
    else     whh = (m < 2) ? (const void*)((const float*)p.dWhh0 + (size_t)m * 262144)
                           : (const void*)((const float*)p.dWhh1 + (size_t)(m - 2) * 262144);
    const void* bb;
    if (bfm) bb = (m < 2) ? (const void*)((const unsigned short*)p.dB0 + m * 1024)
                          : (const void*)((const unsigned short*)p.dB1 + (m - 2) * 1024);
    else     bb = (m < 2) ? (const void*)((const float*)p.dB0 + m * 1024)
                          : (const void*)((const float*)p.dB1 + (m - 2) * 1024);
    if (m == 0)      stage_u128(AH0, y0w + (size_t)1023 * 16384, 256, 0);
    else if (m == 1) stage_u128(AH0, y0w, 256, 128);
    else             stage_u128(AH0, EHL1u + (m - 2) * 8192, 128, 0);
    __syncthreads();
    float* dst = ws + ROF + m * 65536;
    for (int pass = 0; pass < 2; ++pass) {
      const int rowbase = wl6 * 16 + pass * 8;
      uint4 wrA[2][4];
      load_w16_rows(wrA, whh, rowbase, bfm);
      float4 acc[8];
#pragma unroll
      for (int e = 0; e < 8; ++e) acc[e] = make_float4(0.f, 0.f, 0.f, 0.f);
      dot2_t4(acc, AH0, wrA);
      reduce_R(acc, part, dst, bb, rowbase, bfm);
    }
  }
  gbar(ctrs, ++genF);   // ROF visible

  // ============================ decoder prep ===============================
  uint4* DWu4 = (uint4*)(ws + Y0OF);   // dWih1 fp16, overwrites dead y0
  {
    int idx = w * 512 + t;             // 131072 uint4 total
    int dd = idx >> 16, rem = idx & 65535;
    int row = rem >> 6, kc = rem & 63;
    DWu4[idx] = ldw8(p.dWih1, (size_t)dd * 524288 + (size_t)row * 512 + kc * 8, bfm);
  }
  float r1i = 0.f, r1f = 0.f, r1g = 0.f, r1o = 0.f, coldc = 0.f, fwc = 0.f, fcb = 0.f;
  {
    float* R0L  = (float*)UN;          // [2][1024]
    float* WI0L = (float*)(UN + 8192); // [2][1024]
    float* C0L  = (float*)(UN + 16384);// [2][256]
    if (w < 64) {
      const int bq = w;
#pragma unroll
      for (int i = 0; i < 4; ++i) {
        int r = t + i * THR;           // 0..2047
        int dz = r >> 10, rr = r & 1023;
        R0L[r]  = ws[ROF + dz * 65536 + (size_t)bq * 1024 + rr];
        WI0L[r] = ldin(p.dWih0, dz * 1024 + rr, bfm);
      }
      C0L[t >= 512 ? 0 : t] = ws[ECL0 + (t >> 8) * 16384 + (size_t)bq * 256 + (t & 255)];
      const int dd2 = t >> 8, col = t & 255;
      r1i = ws[ROF + (2 + dd2) * 65536 + (size_t)bq * 1024 +       col];
      r1f = ws[ROF + (2 + dd2) * 65536 + (size_t)bq * 1024 + 256 + col];
      r1g = ws[ROF + (2 + dd2) * 65536 + (size_t)bq * 1024 + 512 + col];
      r1o = ws[ROF + (2 + dd2) * 65536 + (size_t)bq * 1024 + 768 + col];
      coldc = ws[ECL1 + dd2 * 16384 + (size_t)bq * 256 + col];
      fwc = ldin(p.fcW, dd2 * 256 + col, bfm);
      fcb = ldin(p.fcb, 0, bfm);
    }
  }
  gbar(ctrs, ++genF);   // DW16 visible

  // ===================== decoder loop: one WG per batch ====================
  if (w < 64) {
    const int bq = w;
    float* R0L  = (float*)UN;
    float* WI0L = (float*)(UN + 8192);
    float* C0L  = (float*)(UN + 16384);
    unsigned* ZV = (unsigned*)(UN + 18432);  // [128] uints = 512 fp16 z
    const int dd2 = t >> 8, col = t & 255;
    const size_t wb0 = (size_t)dd2 * 65536 + (size_t)col * 64;

    // initial z from y = 0
    {
      float gi = R0L[dd2 * 1024 +       col];
      float gf = R0L[dd2 * 1024 + 256 + col];
      float gg = R0L[dd2 * 1024 + 512 + col];
      float go = R0L[dd2 * 1024 + 768 + col];
      float cold = C0L[dd2 * 256 + col];
      float cn = sigm(gf) * cold + sigm(gi) * tanhf(gg);
      float hz = sigm(go) * tanhf(cn);
      ((unsigned short*)ZV)[t] = f2h_u(hz);
    }
    __syncthreads();

    float yp1 = 3.0e38f, yp2 = -3.0e38f;
    for (int st = 0; st < 1024; ++st) {
      // l1 gates for (dd2, col): 4 rows, K=512
      float4 ac0 = {0.f,0.f,0.f,0.f}, ac1 = {0.f,0.f,0.f,0.f};
      float4 ac2 = {0.f,0.f,0.f,0.f}, ac3 = {0.f,0.f,0.f,0.f};
      for (int kc = 0; kc < 64; ++kc) {
        uint4 zv = *(const uint4*)(ZV + kc * 4);
        dot2acc(ac0, zv, DWu4[wb0 +             kc]);
        dot2acc(ac1, zv, DWu4[wb0 + 16384     + kc]);
        dot2acc(ac2, zv, DWu4[wb0 + 2 * 16384 + kc]);
        dot2acc(ac3, zv, DWu4[wb0 + 3 * 16384 + kc]);
      }
      float gi = (ac0.x + ac0.y) + (ac0.z + ac0.w) + r1i;
      float gf = (ac1.x + ac1.y) + (ac1.z + ac1.w) + r1f;
      float gg = (ac2.x + ac2.y) + (ac2.z + ac2.w) + r1g;
      float go = (ac3.x + ac3.y) + (ac3.z + ac3.w) + r1o;
      float cn = sigm(gf) * coldc + sigm(gi) * tanhf(gg);
      float h1 = sigm(go) * tanhf(cn);
      GF[t] = h1 * fwc;
      __syncthreads();
      if (t < 64) {
        const float* q = GF + t;
        GF[t] = ((q[0] + q[64]) + (q[128] + q[192])) +
                ((q[256] + q[320]) + (q[384] + q[448]));
      }
      __syncthreads();
      if (t == 0) {
        float yy = fcb;
        for (int i = 0; i < 64; ++i) yy += GF[i];
        YL[0] = yy;
      }
      __syncthreads();
      float ynew = YL[0];
      if (t == 0) stout(p.out, (size_t)bq * 1024 + st, ynew, bfm);
      if (ynew == yp1) {               // exact fixed point
        for (int t2 = st + 1 + t; t2 < 1024; t2 += THR)
          stout(p.out, (size_t)bq * 1024 + t2, ynew, bfm);
        break;
      }
      if (ynew == yp2) {               // exact period-2 cycle
        for (int t2 = st + 1 + t; t2 < 1024; t2 += THR)
          stout(p.out, (size_t)bq * 1024 + t2, ((t2 - st) & 1) ? yp1 : ynew, bfm);
        break;
      }
      yp2 = yp1; yp1 = ynew;
      if (st < 1023) {
        __syncthreads();               // ZV fully consumed before overwrite
        float gi2 = ynew * WI0L[dd2 * 1024 +       col] + R0L[dd2 * 1024 +       col];
        float gf2 = ynew * WI0L[dd2 * 1024 + 256 + col] + R0L[dd2 * 1024 + 256 + col];
        float gg2 = ynew * WI0L[dd2 * 1024 + 512 + col] + R0L[dd2 * 1024 + 512 + col];
        float go2 = ynew * WI0L[dd2 * 1024 + 768 + col] + R0L[dd2 * 1024 + 768 + col];
        float cold = C0L[dd2 * 256 + col];
        float cn2 = sigm(gf2) * cold + sigm(gi2) * tanhf(gg2);
        float hz = sigm(go2) * tanhf(cn2);
        ((unsigned short*)ZV)[t] = f2h_u(hz);
        __syncthreads();
      }
    }
  }
}

// diagnostic: if ws too small, encode ws_size (MB) into the output signature
__global__ void fill_sig(unsigned short* out, int n, float val) {
  int i = blockIdx.x * 256 + threadIdx.x;
  __hip_bfloat16 b = __float2bfloat16(val);
  if (i < n) out[i] = *reinterpret_cast<unsigned short*>(&b);
}

extern "C" void kernel_launch(void* const* d_in, const int* in_sizes, int n_in,
                              void* d_out, int out_size, void* d_ws, size_t ws_size,
                              hipStream_t stream) {
  (void)in_sizes; (void)n_in;
  if (ws_size < WS_REQ_BYTES) {
    float sig = 2048.0f + (float)(ws_size >> 20);
    fill_sig<<<(out_size + 255) / 256, 256, 0, stream>>>(
        (unsigned short*)d_out, out_size, sig);
    return;
  }
  hipMemsetAsync(d_ws, 0, 8192, stream);  // zero barrier counters

  SeqParams p;
  p.x     = d_in[0];
  p.eWih0 = d_in[1];
  p.eWhh0 = d_in[2];
  p.eB0   = d_in[3];
  p.eWih1 = d_in[4];
  p.eWhh1 = d_in[5];
  p.eB1   = d_in[6];
  p.dWih0 = d_in[7];
  p.dWhh0 = d_in[8];
  p.dB0   = d_in[9];
  p.dWih1 = d_in[10];
  p.dWhh1 = d_in[11];
  p.dB1   = d_in[12];
  p.fcW   = d_in[13];
  p.fcb   = d_in[14];
  p.out   = d_out;
  p.ws    = (float*)d_ws;
  p.ctrs  = (unsigned*)d_ws;

  seq2seq_kernel<<<dim3(NWG), dim3(THR), 0, stream>>>(p);
}

// Round 4
// 7773.078 us; speedup vs baseline: 2.4365x; 2.4365x over previous
//
#include <hip/hip_runtime.h>
#include <hip/hip_bf16.h>
#include <hip/hip_fp16.h>
#include <math.h>

// ---------------------------------------------------------------------------
// Seq2Seq (bi-LSTM encoder x2 + fixed-state decoder), B=64 T=1024 H=256.
// THIS ROUND: zero per-step weight streaming.
//  * Whh fully resident per (dir,b) WG: 768 rows as 3 half-rows/thread in
//    VGPRs (192 regs, static-indexed) + 256 rows in XOR-swizzled LDS;
//    half-dots combined via __shfl_xor(1). Recurrent loop: 0 global loads.
//  * E1 input GEMM (8-step window) reads Wih1 from a pre-TRANSPOSED fp16
//    copy W'[kc][row] in ws -> every load is 64 lanes x consecutive 16B.
//    GW window accumulators fp16 in LDS.
//  * Decoder dWih1 also pre-transposed -> 2 MB/step coalesced.
//  * x row staged to LDS once per WG.
// ---------------------------------------------------------------------------

#define NWG 256
#define THR 512
#define U0S 132      // R-phase A-tile stride in uints

// ws layout (float offsets); first 2048 floats = barrier counters (8 KB)
#define ECL0   2048                 // enc l0 final c (fp32): [dir*16384 + b*256 + k]
#define EHL1   (ECL0 + 32768)       // enc l1 final h packed fp16: uint[dir*8192 + b*128 + t]
#define ECL1   (EHL1 + 16384)       // enc l1 final c (fp32)
#define ROF    (ECL1 + 32768)       // decoder recurrent consts R (fp32): [m*65536 + b*1024 + r]
#define WIH1T  (ROF + 262144)       // transposed fp16 eWih1: uint4[dir*65536 + kc*1024 + row]
#define Y0OF   (WIH1T + 524288)     // packed fp16 y0: uint[t*16384 + b*256 + dir*128 + c]
#define WS_REQ_BYTES ((size_t)(Y0OF + 16777216) * 4)   // ~70.6 MB

struct SeqParams {
  const void *x, *eWih0, *eWhh0, *eB0, *eWih1, *eWhh1, *eB1;
  const void *dWih0, *dWhh0, *dB0, *dWih1, *dWhh1, *dB1, *fcW, *fcb;
  void* out;
  float* ws;
  unsigned* ctrs;
};

typedef _Float16 hlf2 __attribute__((ext_vector_type(2)));

__device__ __forceinline__ float bf2f(unsigned short u) {
  return __uint_as_float(((unsigned)u) << 16);
}
__device__ __forceinline__ float hf2f(unsigned short u) {
  __half_raw r; r.x = u; return __half2float(__half(r));
}
__device__ __forceinline__ unsigned short f2h_u(float f) {
  __half h = __float2half(f);
  return *reinterpret_cast<unsigned short*>(&h);
}
__device__ __forceinline__ float sigm(float v) { return 1.0f / (1.0f + expf(-v)); }

#if __has_builtin(__builtin_amdgcn_fdot2)
__device__ __forceinline__ float fdot2(hlf2 a, hlf2 b, float c) {
  return __builtin_amdgcn_fdot2(a, b, c, false);
}
#else
__device__ __forceinline__ float fdot2(hlf2 a, hlf2 b, float c) {
  return c + (float)a[0] * (float)b[0] + (float)a[1] * (float)b[1];
}
#endif

// a += dot(x, y) over 8 fp16 lanes (4 chained fdot2)
__device__ __forceinline__ float dot1(float a, const uint4& x, const uint4& y) {
  const hlf2* xp = reinterpret_cast<const hlf2*>(&x);
  const hlf2* yp = reinterpret_cast<const hlf2*>(&y);
  a = fdot2(xp[0], yp[0], a);
  a = fdot2(xp[1], yp[1], a);
  a = fdot2(xp[2], yp[2], a);
  a = fdot2(xp[3], yp[3], a);
  return a;
}
__device__ __forceinline__ void dot2acc(float4& a, const uint4& hv, const uint4& wv) {
  const hlf2* hp = reinterpret_cast<const hlf2*>(&hv);
  const hlf2* wp = reinterpret_cast<const hlf2*>(&wv);
  a.x = fdot2(hp[0], wp[0], a.x);
  a.y = fdot2(hp[1], wp[1], a.y);
  a.z = fdot2(hp[2], wp[2], a.z);
  a.w = fdot2(hp[3], wp[3], a.w);
}

__device__ __forceinline__ float ldin(const void* p_, size_t i, int bf) {
  return bf ? bf2f(((const unsigned short*)p_)[i]) : ((const float*)p_)[i];
}
__device__ __forceinline__ void stout(void* o, size_t i, float v, int bf) {
  if (bf) ((__hip_bfloat16*)o)[i] = __float2bfloat16(v);
  else    ((float*)o)[i] = v;
}

// probe storage dtype from x (N(0,1) samples)
__device__ __forceinline__ int detect_bf16(const void* xp) {
  const unsigned* u = (const unsigned*)xp;
  int votes = 0;
#pragma unroll 8
  for (int i = 0; i < 64; ++i) {
    unsigned e = (u[i] >> 7) & 0xFF;
    votes += (e >= 108 && e <= 131) ? 1 : 0;
  }
  return votes >= 32;
}

// ---- full barrier (fenced release/acquire; phase transitions only) ---------
__device__ __forceinline__ void gbar(unsigned* ctrs, unsigned gen) {
  __syncthreads();
  if (threadIdx.x == 0) {
    __hip_atomic_fetch_add(&ctrs[(blockIdx.x & 31) * 32], 1u,
                           __ATOMIC_RELEASE, __HIP_MEMORY_SCOPE_AGENT);
  }
  if (threadIdx.x < 32) {
    while (__hip_atomic_load(&ctrs[threadIdx.x * 32], __ATOMIC_RELAXED,
                             __HIP_MEMORY_SCOPE_AGENT) < gen * 8u) {
      __builtin_amdgcn_s_sleep(1);
    }
    (void)__hip_atomic_load(&ctrs[threadIdx.x * 32], __ATOMIC_ACQUIRE,
                            __HIP_MEMORY_SCOPE_AGENT);
  }
  __syncthreads();
}

// 8-elem chunk of a weight row (bf16 or fp32 global) -> packed fp16 uint4
__device__ __forceinline__ uint4 ldw8(const void* src, size_t off, int bf) {
  union { __half h[8]; uint4 u; } r;
  if (bf) {
    const unsigned short* s = (const unsigned short*)src + off;
    ushort4 a = *reinterpret_cast<const ushort4*>(s);
    ushort4 b = *reinterpret_cast<const ushort4*>(s + 4);
    r.h[0] = __float2half(bf2f(a.x)); r.h[1] = __float2half(bf2f(a.y));
    r.h[2] = __float2half(bf2f(a.z)); r.h[3] = __float2half(bf2f(a.w));
    r.h[4] = __float2half(bf2f(b.x)); r.h[5] = __float2half(bf2f(b.y));
    r.h[6] = __float2half(bf2f(b.z)); r.h[7] = __float2half(bf2f(b.w));
  } else {
    const float* s = (const float*)src + off;
    float4 a = *reinterpret_cast<const float4*>(s);
    float4 b = *reinterpret_cast<const float4*>(s + 4);
    r.h[0] = __float2half(a.x); r.h[1] = __float2half(a.y);
    r.h[2] = __float2half(a.z); r.h[3] = __float2half(a.w);
    r.h[4] = __float2half(b.x); r.h[5] = __float2half(b.y);
    r.h[6] = __float2half(b.z); r.h[7] = __float2half(b.w);
  }
  return r.u;
}

// ---- R-phase helpers (proven; from round 2/3) ------------------------------
__device__ __forceinline__ void stage_u128(unsigned* AH, const unsigned* src,
                                           int ustr, int uoff) {
  const int t = threadIdx.x;
#pragma unroll
  for (int i = 0; i < 4; ++i) {
    int idx = t + i * THR;
    int r = idx >> 5, c4 = (idx & 31) << 2;
    uint4 v = *reinterpret_cast<const uint4*>(src + (size_t)r * ustr + uoff + c4);
    *reinterpret_cast<uint4*>(AH + r * U0S + c4) = v;
  }
}
__device__ __forceinline__ void load_w16_rows(uint4 (&wr)[2][4], const void* src,
                                              int rowbase, int bf) {
  const int t = threadIdx.x, kc = t >> 6, rt = t & 3;
#pragma unroll
  for (int j = 0; j < 2; ++j) {
    size_t rb = (size_t)(rowbase + rt * 2 + j) * 256 + kc * 32;
#pragma unroll
    for (int d = 0; d < 4; ++d) wr[j][d] = ldw8(src, rb + d * 8, bf);
  }
}
__device__ __forceinline__ void dot2_t4(float4* acc, const unsigned* A,
                                        const uint4 (&wr)[2][4]) {
  const int t = threadIdx.x;
  const int kc = t >> 6, bt = (t & 63) >> 2;
#pragma unroll
  for (int d = 0; d < 4; ++d) {
    const int k = kc * 16 + d * 4;
    uint4 h0 = *reinterpret_cast<const uint4*>(A + (bt +  0) * U0S + k);
    uint4 h1 = *reinterpret_cast<const uint4*>(A + (bt + 16) * U0S + k);
    uint4 h2 = *reinterpret_cast<const uint4*>(A + (bt + 32) * U0S + k);
    uint4 h3 = *reinterpret_cast<const uint4*>(A + (bt + 48) * U0S + k);
    dot2acc(acc[0], h0, wr[0][d]); dot2acc(acc[1], h0, wr[1][d]);
    dot2acc(acc[2], h1, wr[0][d]); dot2acc(acc[3], h1, wr[1][d]);
    dot2acc(acc[4], h2, wr[0][d]); dot2acc(acc[5], h2, wr[1][d]);
    dot2acc(acc[6], h3, wr[0][d]); dot2acc(acc[7], h3, wr[1][d]);
  }
}
__device__ __forceinline__ void reduce_R(const float4* acc, float* part, float* dst,
                                         const void* bsrc, int rowbase, int bf) {
  const int t = threadIdx.x;
  const int kc = t >> 6, tile = t & 63;
#pragma unroll
  for (int e = 0; e < 8; ++e) {
    const float4 a = acc[e];
    part[e * 512 + kc * 64 + tile] = (a.x + a.y) + (a.z + a.w);
  }
  __syncthreads();
  {
    const int r = t >> 6, b = t & 63;
    const int tl = (b & 15) * 4 + (r >> 1);
    const float* pp = part + ((b >> 4) * 2 + (r & 1)) * 512 + tl;
    float v = ((pp[0] + pp[64]) + (pp[128] + pp[192])) +
              ((pp[256] + pp[320]) + (pp[384] + pp[448]));
    dst[(size_t)b * 1024 + rowbase + r] = v + ldin(bsrc, rowbase + r, bf);
  }
  __syncthreads();
}

// ---------------------------------------------------------------------------
__global__ void __launch_bounds__(THR, 2) seq2seq_kernel(SeqParams p) {
  // smem layout (160384 B total):
  //  [0,131072)      WLDS: Whh rows 768-1023, 32 uint4/row, XOR-swizzled
  //                  R-phase alias: AH0(33792) + part(16384)
  //                  decoder alias: R0L(8192) WI0L(8192) C0L(2048) ZV(1024)
  //  [131072,139264) YW (E1 window, 512 uint4) / GF fp32[1024] (alias)
  //  [139264,155648) E1: GW fp16[8][1024]; E0: PREWf fp32[1024] + XROW fp32[1024]
  //  [155648,159744) PREB fp32[1024]
  //  [159744,160256) H16 uint[128]
  //  [160256,160384) misc (YL)
  __shared__ __align__(16) char smem[160384];
  uint4* WLDSu4 = (uint4*)smem;
  float* GF     = (float*)(smem + 131072);
  uint4* YWu4   = (uint4*)(smem + 131072);
  unsigned short* GW16 = (unsigned short*)(smem + 139264);
  float* PREWf  = (float*)(smem + 139264);
  float* XROW   = (float*)(smem + 139264 + 4096);
  float* PREB   = (float*)(smem + 155648);
  unsigned* H16 = (unsigned*)(smem + 159744);
  float* YL     = (float*)(smem + 160256);

  const int w = blockIdx.x;
  const int t = threadIdx.x;
  float* ws = p.ws;
  unsigned* ctrs = p.ctrs;
  unsigned* y0w   = (unsigned*)(ws + Y0OF);
  unsigned* EHL1u = (unsigned*)(ws + EHL1);
  uint4* WIH1Tu4  = (uint4*)(ws + WIH1T);
  uint4* DWu4     = (uint4*)(ws + Y0OF);   // decoder transposed dWih1 (after R)
  unsigned genF = 0;
  const int bfm = detect_bf16(p.x);
  const int enc_act = (w < 128);
  const int d = (w >> 6) & 1, b = w & 63;
  const int R0 = t >> 1, hs = t & 1, swz = R0 & 7;

  uint4 wreg3[3][16];   // 3 half-rows (K-half hs) of Whh: rows R0, R0+256, R0+512

  // ============================ E0 prep ====================================
  if (enc_act) {
    const void* whh0 = bfm ? (const void*)((const unsigned short*)p.eWhh0 + (size_t)d * 262144)
                           : (const void*)((const float*)p.eWhh0 + (size_t)d * 262144);
#pragma unroll
    for (int sl = 0; sl < 3; ++sl)
#pragma unroll
      for (int kk = 0; kk < 16; ++kk)
        wreg3[sl][kk] = ldw8(whh0, (size_t)(R0 + sl * 256) * 256 + (size_t)hs * 128 + kk * 8, bfm);
#pragma unroll
    for (int i = 0; i < 16; ++i) {       // WLDS rows 768-1023, swizzled
      int idx = t + i * 512;
      int row = idx >> 5, j = idx & 31;
      WLDSu4[row * 32 + (j ^ (row & 7))] =
          ldw8(whh0, (size_t)(768 + row) * 256 + j * 8, bfm);
    }
#pragma unroll
    for (int q = 0; q < 2; ++q) {
      PREB[t + q * 512]  = ldin(p.eB0,   d * 1024 + t + q * 512, bfm);
      PREWf[t + q * 512] = ldin(p.eWih0, d * 1024 + t + q * 512, bfm);
      XROW[t + q * 512]  = ldin(p.x, (size_t)b * 1024 + t + q * 512, bfm);
    }
    if (t < 128) H16[t] = 0u;
  }
  gbar(ctrs, ++genF);

  // ====================== E0: 1024 steps, zero global loads ================
  if (enc_act) {
    float cc = 0.f;
    const uint4* wl = WLDSu4 + R0 * 32;
    for (int st = 0; st < 1024; ++st) {
      const int tt = d ? (1023 - st) : st;
      float s0 = 0.f, s1 = 0.f, s2 = 0.f, s3 = 0.f;
#pragma unroll
      for (int i2 = 0; i2 < 8; ++i2) {
        uint4 h0 = *(const uint4*)(H16 + hs * 64 + i2 * 8);
        uint4 h1 = *(const uint4*)(H16 + hs * 64 + i2 * 8 + 4);
        uint4 wl0 = wl[(hs * 16 + i2 * 2)     ^ swz];
        uint4 wl1 = wl[(hs * 16 + i2 * 2 + 1) ^ swz];
        s0 = dot1(s0, h0, wreg3[0][i2 * 2]); s0 = dot1(s0, h1, wreg3[0][i2 * 2 + 1]);
        s1 = dot1(s1, h0, wreg3[1][i2 * 2]); s1 = dot1(s1, h1, wreg3[1][i2 * 2 + 1]);
        s2 = dot1(s2, h0, wreg3[2][i2 * 2]); s2 = dot1(s2, h1, wreg3[2][i2 * 2 + 1]);
        s3 = dot1(s3, h0, wl0);              s3 = dot1(s3, h1, wl1);
      }
      s0 += __shfl_xor(s0, 1, 64);
      s1 += __shfl_xor(s1, 1, 64);
      s2 += __shfl_xor(s2, 1, 64);
      s3 += __shfl_xor(s3, 1, 64);
      if (hs == 0) {
        GF[R0] = s0; GF[R0 + 256] = s1; GF[R0 + 512] = s2; GF[768 + R0] = s3;
      }
      __syncthreads();
      if (t < 256) {
        float xv = XROW[tt];
        float gi = GF[t]       + PREB[t]       + xv * PREWf[t];
        float gf = GF[256 + t] + PREB[256 + t] + xv * PREWf[256 + t];
        float gg = GF[512 + t] + PREB[512 + t] + xv * PREWf[512 + t];
        float go = GF[768 + t] + PREB[768 + t] + xv * PREWf[768 + t];
        float cn = sigm(gf) * cc + sigm(gi) * tanhf(gg);
        float hn = sigm(go) * tanhf(cn);
        cc = cn;
        ((unsigned short*)H16)[t] = f2h_u(hn);
        if (st == 1023) ws[ECL0 + d * 16384 + b * 256 + t] = cn;
      }
      __syncthreads();
      if (t < 128) y0w[(size_t)tt * 16384 + (size_t)b * 256 + d * 128 + t] = H16[t];
    }
  }
  gbar(ctrs, ++genF);   // y0 / ECL0 visible

  // ============================ E1 prep ====================================
  {
    // transposed fp16 Wih1 -> ws (all 256 WGs, coalesced writes)
#pragma unroll
    for (int i = 0; i < 2; ++i) {
      int idx = w * 512 + t + i * 0;     // 512 per WG, do in one shot below
      (void)idx;
    }
    {
      int idx = w * 512 + t;             // 131072 uint4 total
      int dd = idx >> 16, rem = idx & 65535;
      int kc = rem >> 10, row = rem & 1023;
      WIH1Tu4[idx] = ldw8(p.eWih1, (size_t)dd * 524288 + (size_t)row * 512 + kc * 8, bfm);
    }
    if (enc_act) {
      const void* whh1 = bfm ? (const void*)((const unsigned short*)p.eWhh1 + (size_t)d * 262144)
                             : (const void*)((const float*)p.eWhh1 + (size_t)d * 262144);
#pragma unroll
      for (int sl = 0; sl < 3; ++sl)
#pragma unroll
        for (int kk = 0; kk < 16; ++kk)
          wreg3[sl][kk] = ldw8(whh1, (size_t)(R0 + sl * 256) * 256 + (size_t)hs * 128 + kk * 8, bfm);
#pragma unroll
      for (int i = 0; i < 16; ++i) {
        int idx = t + i * 512;
        int row = idx >> 5, j = idx & 31;
        WLDSu4[row * 32 + (j ^ (row & 7))] =
            ldw8(whh1, (size_t)(768 + row) * 256 + j * 8, bfm);
      }
#pragma unroll
      for (int q = 0; q < 2; ++q)
        PREB[t + q * 512] = ldin(p.eB1, d * 1024 + t + q * 512, bfm);
      if (t < 128) H16[t] = 0u;
    }
  }
  gbar(ctrs, ++genF);   // W' + y0 visible

  // ====================== E1: 1024 steps ===================================
  if (enc_act) {
    float cc = 0.f;
    const uint4* wl = WLDSu4 + R0 * 32;
    const uint4* Wt = WIH1Tu4 + (size_t)d * 65536;
    for (int st = 0; st < 1024; ++st) {
      if ((st & 7) == 0) {
        // build y0 window (8 steps x 64 uint4), coalesced
        {
          int s = t >> 6, kcc = t & 63;
          int tw = d ? (1023 - (st + s)) : (st + s);
          YWu4[s * 64 + kcc] =
              *(const uint4*)(y0w + (size_t)tw * 16384 + (size_t)b * 256 + kcc * 4);
        }
        __syncthreads();
        // window GEMM: rows t and t+512, 8 steps, K=512 (coalesced W' loads)
        float a0[8], a1[8];
#pragma unroll
        for (int s = 0; s < 8; ++s) { a0[s] = 0.f; a1[s] = 0.f; }
        for (int kc = 0; kc < 64; ++kc) {
          uint4 w0 = Wt[kc * 1024 + t];
          uint4 w1 = Wt[kc * 1024 + 512 + t];
#pragma unroll
          for (int s = 0; s < 8; ++s) {
            uint4 yv = YWu4[s * 64 + kc];
            a0[s] = dot1(a0[s], yv, w0);
            a1[s] = dot1(a1[s], yv, w1);
          }
        }
#pragma unroll
        for (int s = 0; s < 8; ++s) {
          GW16[s * 1024 + t]       = f2h_u(a0[s]);
          GW16[s * 1024 + 512 + t] = f2h_u(a1[s]);
        }
        __syncthreads();   // GW visible; YW dead -> GF may overwrite
      }
      float s0 = 0.f, s1 = 0.f, s2 = 0.f, s3 = 0.f;
#pragma unroll
      for (int i2 = 0; i2 < 8; ++i2) {
        uint4 h0 = *(const uint4*)(H16 + hs * 64 + i2 * 8);
        uint4 h1 = *(const uint4*)(H16 + hs * 64 + i2 * 8 + 4);
        uint4 wl0 = wl[(hs * 16 + i2 * 2)     ^ swz];
        uint4 wl1 = wl[(hs * 16 + i2 * 2 + 1) ^ swz];
        s0 = dot1(s0, h0, wreg3[0][i2 * 2]); s0 = dot1(s0, h1, wreg3[0][i2 * 2 + 1]);
        s1 = dot1(s1, h0, wreg3[1][i2 * 2]); s1 = dot1(s1, h1, wreg3[1][i2 * 2 + 1]);
        s2 = dot1(s2, h0, wreg3[2][i2 * 2]); s2 = dot1(s2, h1, wreg3[2][i2 * 2 + 1]);
        s3 = dot1(s3, h0, wl0);              s3 = dot1(s3, h1, wl1);
      }
      s0 += __shfl_xor(s0, 1, 64);
      s1 += __shfl_xor(s1, 1, 64);
      s2 += __shfl_xor(s2, 1, 64);
      s3 += __shfl_xor(s3, 1, 64);
      if (hs == 0) {
        GF[R0] = s0; GF[R0 + 256] = s1; GF[R0 + 512] = s2; GF[768 + R0] = s3;
      }
      __syncthreads();
      if (t < 256) {
        const int sl = (st & 7) * 1024;
        float gi = GF[t]       + PREB[t]       + hf2f(GW16[sl + t]);
        float gf = GF[256 + t] + PREB[256 + t] + hf2f(GW16[sl + 256 + t]);
        float gg = GF[512 + t] + PREB[512 + t] + hf2f(GW16[sl + 512 + t]);
        float go = GF[768 + t] + PREB[768 + t] + hf2f(GW16[sl + 768 + t]);
        float cn = sigm(gf) * cc + sigm(gi) * tanhf(gg);
        float hn = sigm(go) * tanhf(cn);
        cc = cn;
        ((unsigned short*)H16)[t] = f2h_u(hn);
        if (st == 1023) ws[ECL1 + d * 16384 + b * 256 + t] = cn;
      }
      __syncthreads();
      if (st == 1023 && t < 128) EHL1u[d * 8192 + b * 128 + t] = H16[t];
    }
  }
  gbar(ctrs, ++genF);   // EHL1/ECL1 visible

  // ===================== decoder recurrent consts R ========================
  {
    unsigned* AH0 = (unsigned*)smem;
    float* part = (float*)(smem + 33792);
    const int m = w >> 6, wl6 = w & 63;
    const void* whh;
    if (bfm) whh = (m < 2) ? (const void*)((const unsigned short*)p.dWhh0 + (size_t)m * 262144)
                           : (const void*)((const unsigned short*)p.dWhh1 + (size_t)(m - 2) * 262144);
    else     whh = (m < 2) ? (const void*)((const float*)p.dWhh0 + (size_t)m * 262144)
                           : (const void*)((const float*)p.dWhh1 + (size_t)(m - 2) * 262144);
    const void* bb;
    if (bfm) bb = (m < 2) ? (const void*)((const unsigned short*)p.dB0 + m * 1024)
                          : (const void*)((const unsigned short*)p.dB1 + (m - 2) * 1024);
    else     bb = (m < 2) ? (const void*)((const float*)p.dB0 + m * 1024)
                          : (const void*)((const float*)p.dB1 + (m - 2) * 1024);
    if (m == 0)      stage_u128(AH0, y0w + (size_t)1023 * 16384, 256, 0);
    else if (m == 1) stage_u128(AH0, y0w, 256, 128);
    else             stage_u128(AH0, EHL1u + (m - 2) * 8192, 128, 0);
    __syncthreads();
    float* dst = ws + ROF + m * 65536;
    for (int pass = 0; pass < 2; ++pass) {
      const int rowbase = wl6 * 16 + pass * 8;
      uint4 wrA[2][4];
      load_w16_rows(wrA, whh, rowbase, bfm);
      float4 acc[8];
#pragma unroll
      for (int e = 0; e < 8; ++e) acc[e] = make_float4(0.f, 0.f, 0.f, 0.f);
      dot2_t4(acc, AH0, wrA);
      reduce_R(acc, part, dst, bb, rowbase, bfm);
    }
  }
  gbar(ctrs, ++genF);   // ROF visible

  // ============================ decoder prep ===============================
  {
    // transposed fp16 dWih1 -> ws (overwrites dead y0 head)
    int idx = w * 512 + t;               // 131072 uint4 total
    int dd = idx >> 16, rem = idx & 65535;
    int kc = rem >> 10, row = rem & 1023;
    DWu4[idx] = ldw8(p.dWih1, (size_t)dd * 524288 + (size_t)row * 512 + kc * 8, bfm);
  }
  float r1i = 0.f, r1f = 0.f, r1g = 0.f, r1o = 0.f, coldc = 0.f, fwc = 0.f, fcb = 0.f;
  {
    float* R0L  = (float*)smem;          // [2][1024]
    float* WI0L = (float*)(smem + 8192); // [2][1024]
    float* C0L  = (float*)(smem + 16384);// [2][256]
    if (w < 64) {
      const int bq = w;
#pragma unroll
      for (int i = 0; i < 4; ++i) {
        int r = t + i * THR;             // 0..2047
        int dz = r >> 10, rr = r & 1023;
        R0L[r]  = ws[ROF + dz * 65536 + (size_t)bq * 1024 + rr];
        WI0L[r] = ldin(p.dWih0, dz * 1024 + rr, bfm);
      }
      C0L[t >= 512 ? 0 : t] = ws[ECL0 + (t >> 8) * 16384 + (size_t)bq * 256 + (t & 255)];
      const int dd2 = t >> 8, col = t & 255;
      r1i = ws[ROF + (2 + dd2) * 65536 + (size_t)bq * 1024 +       col];
      r1f = ws[ROF + (2 + dd2) * 65536 + (size_t)bq * 1024 + 256 + col];
      r1g = ws[ROF + (2 + dd2) * 65536 + (size_t)bq * 1024 + 512 + col];
      r1o = ws[ROF + (2 + dd2) * 65536 + (size_t)bq * 1024 + 768 + col];
      coldc = ws[ECL1 + dd2 * 16384 + (size_t)bq * 256 + col];
      fwc = ldin(p.fcW, dd2 * 256 + col, bfm);
      fcb = ldin(p.fcb, 0, bfm);
    }
  }
  gbar(ctrs, ++genF);   // DW' visible

  // ===================== decoder loop: one WG per batch ====================
  if (w < 64) {
    const int bq = w;
    float* R0L  = (float*)smem;
    float* WI0L = (float*)(smem + 8192);
    float* C0L  = (float*)(smem + 16384);
    unsigned* ZV = (unsigned*)(smem + 18432);   // 256 uints = 512 fp16 z
    const int dd2 = t >> 8, col = t & 255;
    const uint4* DWt = DWu4 + (size_t)dd2 * 65536;

    // initial z from y = 0
    {
      float gi = R0L[dd2 * 1024 +       col];
      float gf = R0L[dd2 * 1024 + 256 + col];
      float gg = R0L[dd2 * 1024 + 512 + col];
      float go = R0L[dd2 * 1024 + 768 + col];
      float cold = C0L[dd2 * 256 + col];
      float cn = sigm(gf) * cold + sigm(gi) * tanhf(gg);
      float hz = sigm(go) * tanhf(cn);
      ((unsigned short*)ZV)[t] = f2h_u(hz);
    }
    __syncthreads();

    float yp1 = 3.0e38f, yp2 = -3.0e38f;
    for (int st = 0; st < 1024; ++st) {
      // l1 gates for (dd2, col): 4 rows, K=512, coalesced DW' loads
      float ai = 0.f, af = 0.f, ag = 0.f, ao = 0.f;
      for (int kc = 0; kc < 64; ++kc) {
        uint4 zv = *(const uint4*)(ZV + kc * 4);
        uint4 w0 = DWt[kc * 1024 +       col];
        uint4 w1 = DWt[kc * 1024 + 256 + col];
        uint4 w2 = DWt[kc * 1024 + 512 + col];
        uint4 w3 = DWt[kc * 1024 + 768 + col];
        ai = dot1(ai, zv, w0);
        af = dot1(af, zv, w1);
        ag = dot1(ag, zv, w2);
        ao = dot1(ao, zv, w3);
      }
      float gi = ai + r1i, gf = af + r1f, gg = ag + r1g, go = ao + r1o;
      float cn = sigm(gf) * coldc + sigm(gi) * tanhf(gg);
      float h1 = sigm(go) * tanhf(cn);
      GF[t] = h1 * fwc;
      __syncthreads();
      if (t < 64) {
        const float* q = GF + t;
        GF[t] = ((q[0] + q[64]) + (q[128] + q[192])) +
                ((q[256] + q[320]) + (q[384] + q[448]));
      }
      __syncthreads();
      if (t == 0) {
        float yy = fcb;
        for (int i = 0; i < 64; ++i) yy += GF[i];
        YL[0] = yy;
      }
      __syncthreads();
      float ynew = YL[0];
      if (t == 0) stout(p.out, (size_t)bq * 1024 + st, ynew, bfm);
      if (ynew == yp1) {               // exact fixed point
        for (int t2 = st + 1 + t; t2 < 1024; t2 += THR)
          stout(p.out, (size_t)bq * 1024 + t2, ynew, bfm);
        break;
      }
      if (ynew == yp2) {               // exact period-2 cycle
        for (int t2 = st + 1 + t; t2 < 1024; t2 += THR)
          stout(p.out, (size_t)bq * 1024 + t2, ((t2 - st) & 1) ? yp1 : ynew, bfm);
        break;
      }
      yp2 = yp1; yp1 = ynew;
      if (st < 1023) {
        __syncthreads();               // ZV fully consumed before overwrite
        float gi2 = ynew * WI0L[dd2 * 1024 +       col] + R0L[dd2 * 1024 +       col];
        float gf2 = ynew * WI0L[dd2 * 1024 + 256 + col] + R0L[dd2 * 1024 + 256 + col];
        float gg2 = ynew * WI0L[dd2 * 1024 + 512 + col] + R0L[dd2 * 1024 + 512 + col];
        float go2 = ynew * WI0L[dd2 * 1024 + 768 + col] + R0L[dd2 * 1024 + 768 + col];
        float cold = C0L[dd2 * 256 + col];
        float cn2 = sigm(gf2) * cold + sigm(gi2) * tanhf(gg2);
        float hz = sigm(go2) * tanhf(cn2);
        ((unsigned short*)ZV)[t] = f2h_u(hz);
        __syncthreads();
      }
    }
  }
}

// diagnostic: if ws too small, encode ws_size (MB) into the output signature
__global__ void fill_sig(unsigned short* out, int n, float val) {
  int i = blockIdx.x * 256 + threadIdx.x;
  __hip_bfloat16 b = __float2bfloat16(val);
  if (i < n) out[i] = *reinterpret_cast<unsigned short*>(&b);
}

extern "C" void kernel_launch(void* const* d_in, const int* in_sizes, int n_in,
                              void* d_out, int out_size, void* d_ws, size_t ws_size,
                              hipStream_t stream) {
  (void)in_sizes; (void)n_in;
  if (ws_size < WS_REQ_BYTES) {
    float sig = 2048.0f + (float)(ws_size >> 20);
    fill_sig<<<(out_size + 255) / 256, 256, 0, stream>>>(
        (unsigned short*)d_out, out_size, sig);
    return;
  }
  hipMemsetAsync(d_ws, 0, 8192, stream);  // zero barrier counters

  SeqParams p;
  p.x     = d_in[0];
  p.eWih0 = d_in[1];
  p.eWhh0 = d_in[2];
  p.eB0   = d_in[3];
  p.eWih1 = d_in[4];
  p.eWhh1 = d_in[5];
  p.eB1   = d_in[6];
  p.dWih0 = d_in[7];
  p.dWhh0 = d_in[8];
  p.dB0   = d_in[9];
  p.dWih1 = d_in[10];
  p.dWhh1 = d_in[11];
  p.dB1   = d_in[12];
  p.fcW   = d_in[13];
  p.fcb   = d_in[14];
  p.out   = d_out;
  p.ws    = (float*)d_ws;
  p.ctrs  = (unsigned*)d_ws;

  seq2seq_kernel<<<dim3(NWG), dim3(THR), 0, stream>>>(p);
}

// Round 5
// 5977.217 us; speedup vs baseline: 3.1685x; 1.3005x over previous
//
#include <hip/hip_runtime.h>
#include <hip/hip_bf16.h>
#include <hip/hip_fp16.h>
#include <math.h>

// ---------------------------------------------------------------------------
// Seq2Seq (bi-LSTM encoder x2 + fixed-state decoder), B=64 T=1024 H=256.
// Round 5:
//  * E1 input GEMM offloaded to the 128 previously-idle WGs (producers):
//    GW = y0 @ Wih1^T computed window(8 steps)-ahead into a depth-2 ring in
//    ws, published via sc1 stores + produced-counter; consumers poll once
//    per window. E1's serial chain = recurrent dot + cell only.
//  * Fast branch-free sigm/tanh via v_exp_f32 + v_rcp_f32.
//  * Batched 8-wide LDS weight/h loads in the dot; GF writes split across
//    both half-lanes; waves_per_eu(2,2) to unlock the 256-VGPR budget.
// ---------------------------------------------------------------------------

#define NWG 256
#define THR 512
#define U0S 132      // R-phase A-tile stride in uints

// ws layout (float offsets); first 2048 floats = barrier counters (8 KB)
#define ECL0   2048                 // enc l0 final c (fp32): [dir*16384 + b*256 + k]
#define EHL1   (ECL0 + 32768)       // enc l1 final h packed fp16: uint[dir*8192 + b*128 + t]
#define ECL1   (EHL1 + 16384)       // enc l1 final c (fp32)
#define ROF    (ECL1 + 32768)       // decoder recurrent consts R (fp32): [m*65536 + b*1024 + r]
#define WIH1T  (ROF + 262144)       // transposed fp16 eWih1: uint4[dir*65536 + kc*1024 + row]
#define GWR    (WIH1T + 524288)     // GW ring: uint[chain*8192 + slot*4096 + s*512 + g]
#define PCF    (GWR + 1048576)      // flags: uint[chain*64]=produced, [chain*64+32]=consumed
#define Y0OF   (PCF + 8192)         // packed fp16 y0: uint[t*16384 + b*256 + dir*128 + c]
#define WS_REQ_BYTES ((size_t)(Y0OF + 16777216) * 4)   // ~71.4 MB

struct SeqParams {
  const void *x, *eWih0, *eWhh0, *eB0, *eWih1, *eWhh1, *eB1;
  const void *dWih0, *dWhh0, *dB0, *dWih1, *dWhh1, *dB1, *fcW, *fcb;
  void* out;
  float* ws;
  unsigned* ctrs;
};

typedef _Float16 hlf2 __attribute__((ext_vector_type(2)));

__device__ __forceinline__ float bf2f(unsigned short u) {
  return __uint_as_float(((unsigned)u) << 16);
}
__device__ __forceinline__ float hf2f(unsigned short u) {
  __half_raw r; r.x = u; return __half2float(__half(r));
}
__device__ __forceinline__ unsigned short f2h_u(float f) {
  __half h = __float2half(f);
  return *reinterpret_cast<unsigned short*>(&h);
}

// ---- fast branch-free transcendentals (v_exp_f32 / v_rcp_f32) --------------
__device__ __forceinline__ float fexp2(float x) {
#if __has_builtin(__builtin_amdgcn_exp2f)
  return __builtin_amdgcn_exp2f(x);
#else
  return exp2f(x);
#endif
}
__device__ __forceinline__ float frcp(float x) {
#if __has_builtin(__builtin_amdgcn_rcpf)
  return __builtin_amdgcn_rcpf(x);
#else
  return 1.0f / x;
#endif
}
__device__ __forceinline__ float sigm(float v) {
  return frcp(1.0f + fexp2(v * -1.44269504f));
}
__device__ __forceinline__ float ftanh(float v) {
  return fmaf(-2.0f, frcp(1.0f + fexp2(v * 2.88539008f)), 1.0f);
}

#if __has_builtin(__builtin_amdgcn_fdot2)
__device__ __forceinline__ float fdot2(hlf2 a, hlf2 b, float c) {
  return __builtin_amdgcn_fdot2(a, b, c, false);
}
#else
__device__ __forceinline__ float fdot2(hlf2 a, hlf2 b, float c) {
  return c + (float)a[0] * (float)b[0] + (float)a[1] * (float)b[1];
}
#endif

// a += dot(x, y) over 8 fp16 lanes (4 chained fdot2)
__device__ __forceinline__ float dot1(float a, const uint4& x, const uint4& y) {
  const hlf2* xp = reinterpret_cast<const hlf2*>(&x);
  const hlf2* yp = reinterpret_cast<const hlf2*>(&y);
  a = fdot2(xp[0], yp[0], a);
  a = fdot2(xp[1], yp[1], a);
  a = fdot2(xp[2], yp[2], a);
  a = fdot2(xp[3], yp[3], a);
  return a;
}
__device__ __forceinline__ void dot2acc(float4& a, const uint4& hv, const uint4& wv) {
  const hlf2* hp = reinterpret_cast<const hlf2*>(&hv);
  const hlf2* wp = reinterpret_cast<const hlf2*>(&wv);
  a.x = fdot2(hp[0], wp[0], a.x);
  a.y = fdot2(hp[1], wp[1], a.y);
  a.z = fdot2(hp[2], wp[2], a.z);
  a.w = fdot2(hp[3], wp[3], a.w);
}

__device__ __forceinline__ float ldin(const void* p_, size_t i, int bf) {
  return bf ? bf2f(((const unsigned short*)p_)[i]) : ((const float*)p_)[i];
}
__device__ __forceinline__ void stout(void* o, size_t i, float v, int bf) {
  if (bf) ((__hip_bfloat16*)o)[i] = __float2bfloat16(v);
  else    ((float*)o)[i] = v;
}

// probe storage dtype from x (N(0,1) samples)
__device__ __forceinline__ int detect_bf16(const void* xp) {
  const unsigned* u = (const unsigned*)xp;
  int votes = 0;
#pragma unroll 8
  for (int i = 0; i < 64; ++i) {
    unsigned e = (u[i] >> 7) & 0xFF;
    votes += (e >= 108 && e <= 131) ? 1 : 0;
  }
  return votes >= 32;
}

// ---- full barrier (fenced release/acquire; phase transitions only) ---------
__device__ __forceinline__ void gbar(unsigned* ctrs, unsigned gen) {
  __syncthreads();
  if (threadIdx.x == 0) {
    __hip_atomic_fetch_add(&ctrs[(blockIdx.x & 31) * 32], 1u,
                           __ATOMIC_RELEASE, __HIP_MEMORY_SCOPE_AGENT);
  }
  if (threadIdx.x < 32) {
    while (__hip_atomic_load(&ctrs[threadIdx.x * 32], __ATOMIC_RELAXED,
                             __HIP_MEMORY_SCOPE_AGENT) < gen * 8u) {
      __builtin_amdgcn_s_sleep(1);
    }
    (void)__hip_atomic_load(&ctrs[threadIdx.x * 32], __ATOMIC_ACQUIRE,
                            __HIP_MEMORY_SCOPE_AGENT);
  }
  __syncthreads();
}

// 8-elem chunk of a weight row (bf16 or fp32 global) -> packed fp16 uint4
__device__ __forceinline__ uint4 ldw8(const void* src, size_t off, int bf) {
  union { __half h[8]; uint4 u; } r;
  if (bf) {
    const unsigned short* s = (const unsigned short*)src + off;
    ushort4 a = *reinterpret_cast<const ushort4*>(s);
    ushort4 b = *reinterpret_cast<const ushort4*>(s + 4);
    r.h[0] = __float2half(bf2f(a.x)); r.h[1] = __float2half(bf2f(a.y));
    r.h[2] = __float2half(bf2f(a.z)); r.h[3] = __float2half(bf2f(a.w));
    r.h[4] = __float2half(bf2f(b.x)); r.h[5] = __float2half(bf2f(b.y));
    r.h[6] = __float2half(bf2f(b.z)); r.h[7] = __float2half(bf2f(b.w));
  } else {
    const float* s = (const float*)src + off;
    float4 a = *reinterpret_cast<const float4*>(s);
    float4 b = *reinterpret_cast<const float4*>(s + 4);
    r.h[0] = __float2half(a.x); r.h[1] = __float2half(a.y);
    r.h[2] = __float2half(a.z); r.h[3] = __float2half(a.w);
    r.h[4] = __float2half(b.x); r.h[5] = __float2half(b.y);
    r.h[6] = __float2half(b.z); r.h[7] = __float2half(b.w);
  }
  return r.u;
}

// ---- R-phase helpers (proven; from rounds 2-4) -----------------------------
__device__ __forceinline__ void stage_u128(unsigned* AH, const unsigned* src,
                                           int ustr, int uoff) {
  const int t = threadIdx.x;
#pragma unroll
  for (int i = 0; i < 4; ++i) {
    int idx = t + i * THR;
    int r = idx >> 5, c4 = (idx & 31) << 2;
    uint4 v = *reinterpret_cast<const uint4*>(src + (size_t)r * ustr + uoff + c4);
    *reinterpret_cast<uint4*>(AH + r * U0S + c4) = v;
  }
}
__device__ __forceinline__ void load_w16_rows(uint4 (&wr)[2][4], const void* src,
                                              int rowbase, int bf) {
  const int t = threadIdx.x, kc = t >> 6, rt = t & 3;
#pragma unroll
  for (int j = 0; j < 2; ++j) {
    size_t rb = (size_t)(rowbase + rt * 2 + j) * 256 + kc * 32;
#pragma unroll
    for (int d = 0; d < 4; ++d) wr[j][d] = ldw8(src, rb + d * 8, bf);
  }
}
__device__ __forceinline__ void dot2_t4(float4* acc, const unsigned* A,
                                        const uint4 (&wr)[2][4]) {
  const int t = threadIdx.x;
  const int kc = t >> 6, bt = (t & 63) >> 2;
#pragma unroll
  for (int d = 0; d < 4; ++d) {
    const int k = kc * 16 + d * 4;
    uint4 h0 = *reinterpret_cast<const uint4*>(A + (bt +  0) * U0S + k);
    uint4 h1 = *reinterpret_cast<const uint4*>(A + (bt + 16) * U0S + k);
    uint4 h2 = *reinterpret_cast<const uint4*>(A + (bt + 32) * U0S + k);
    uint4 h3 = *reinterpret_cast<const uint4*>(A + (bt + 48) * U0S + k);
    dot2acc(acc[0], h0, wr[0][d]); dot2acc(acc[1], h0, wr[1][d]);
    dot2acc(acc[2], h1, wr[0][d]); dot2acc(acc[3], h1, wr[1][d]);
    dot2acc(acc[4], h2, wr[0][d]); dot2acc(acc[5], h2, wr[1][d]);
    dot2acc(acc[6], h3, wr[0][d]); dot2acc(acc[7], h3, wr[1][d]);
  }
}
__device__ __forceinline__ void reduce_R(const float4* acc, float* part, float* dst,
                                         const void* bsrc, int rowbase, int bf) {
  const int t = threadIdx.x;
  const int kc = t >> 6, tile = t & 63;
#pragma unroll
  for (int e = 0; e < 8; ++e) {
    const float4 a = acc[e];
    part[e * 512 + kc * 64 + tile] = (a.x + a.y) + (a.z + a.w);
  }
  __syncthreads();
  {
    const int r = t >> 6, b = t & 63;
    const int tl = (b & 15) * 4 + (r >> 1);
    const float* pp = part + ((b >> 4) * 2 + (r & 1)) * 512 + tl;
    float v = ((pp[0] + pp[64]) + (pp[128] + pp[192])) +
              ((pp[256] + pp[320]) + (pp[384] + pp[448]));
    dst[(size_t)b * 1024 + rowbase + r] = v + ldin(bsrc, rowbase + r, bf);
  }
  __syncthreads();
}

// ---------------------------------------------------------------------------
__global__ void __launch_bounds__(THR, 2)
__attribute__((amdgpu_waves_per_eu(2, 2)))
seq2seq_kernel(SeqParams p) {
  // smem (148224 B):
  //  [0,131072)       WLDS (Whh rows 768-1023, swizzled)   [consumers E0/E1]
  //                   aliases: producer YW [0,8192) | R: AH0+part | dec: R0L..ZV
  //  [131072,135168)  GF fp32[1024]
  //  [135168,139264)  PREB fp32[1024]
  //  [139264,143360)  PREWf fp32[1024]   (E0)
  //  [143360,147456)  XROW fp32[1024]    (E0)
  //  [147456,147968)  H16 uint[128]
  //  [147968,148224)  YL
  __shared__ __align__(16) char smem[148224];
  uint4* WLDSu4 = (uint4*)smem;
  float* GF     = (float*)(smem + 131072);
  float* PREB   = (float*)(smem + 135168);
  float* PREWf  = (float*)(smem + 139264);
  float* XROW   = (float*)(smem + 143360);
  unsigned* H16 = (unsigned*)(smem + 147456);
  float* YL     = (float*)(smem + 147968);

  const int w = blockIdx.x;
  const int t = threadIdx.x;
  float* ws = p.ws;
  unsigned* ctrs = p.ctrs;
  unsigned* y0w   = (unsigned*)(ws + Y0OF);
  unsigned* EHL1u = (unsigned*)(ws + EHL1);
  uint4* WIH1Tu4  = (uint4*)(ws + WIH1T);
  unsigned* GWu   = (unsigned*)(ws + GWR);
  unsigned* flg   = (unsigned*)(ws + PCF);
  uint4* DWu4     = (uint4*)(ws + Y0OF);   // decoder transposed dWih1 (after R)
  unsigned genF = 0;
  const int bfm = detect_bf16(p.x);
  const int enc_act = (w < 128);
  const int d = (w >> 6) & 1, b = w & 63;
  const int R0 = t >> 1, hs = t & 1, swz = R0 & 7;

  uint4 wreg3[3][16];   // 3 half-rows (K-half hs) of Whh: rows R0, R0+256, R0+512

  // ============================ E0 prep ====================================
  {
    if (w == 0) {                         // reset producer/consumer flags
      for (int i = t; i < 8192; i += THR) flg[i] = 0u;
    }
    if (enc_act) {
      const void* whh0 = bfm ? (const void*)((const unsigned short*)p.eWhh0 + (size_t)d * 262144)
                             : (const void*)((const float*)p.eWhh0 + (size_t)d * 262144);
#pragma unroll
      for (int sl = 0; sl < 3; ++sl)
#pragma unroll
        for (int kk = 0; kk < 16; ++kk)
          wreg3[sl][kk] = ldw8(whh0, (size_t)(R0 + sl * 256) * 256 + (size_t)hs * 128 + kk * 8, bfm);
#pragma unroll
      for (int i = 0; i < 16; ++i) {      // WLDS rows 768-1023, swizzled
        int idx = t + i * 512;
        int row = idx >> 5, j = idx & 31;
        WLDSu4[row * 32 + (j ^ (row & 7))] =
            ldw8(whh0, (size_t)(768 + row) * 256 + j * 8, bfm);
      }
#pragma unroll
      for (int q = 0; q < 2; ++q) {
        PREB[t + q * 512]  = ldin(p.eB0,   d * 1024 + t + q * 512, bfm);
        PREWf[t + q * 512] = ldin(p.eWih0, d * 1024 + t + q * 512, bfm);
        XROW[t + q * 512]  = ldin(p.x, (size_t)b * 1024 + t + q * 512, bfm);
      }
      if (t < 128) H16[t] = 0u;
    }
  }
  gbar(ctrs, ++genF);

  // ====================== E0: 1024 steps, zero global loads ================
  if (enc_act) {
    float cc = 0.f;
    const uint4* wl = WLDSu4 + R0 * 32;
    for (int st = 0; st < 1024; ++st) {
      const int tt = d ? (1023 - st) : st;
      float s0 = 0.f, s1 = 0.f, s2 = 0.f, s3 = 0.f;
#pragma unroll
      for (int hb = 0; hb < 2; ++hb) {
        uint4 wlv[8], hvv[8];
#pragma unroll
        for (int i = 0; i < 8; ++i) {
          int ii = hb * 8 + i;
          wlv[i] = wl[(hs * 16 + ii) ^ swz];
          hvv[i] = *(const uint4*)(H16 + hs * 64 + ii * 4);
        }
#pragma unroll
        for (int i = 0; i < 8; ++i) {
          int ii = hb * 8 + i;
          s0 = dot1(s0, hvv[i], wreg3[0][ii]);
          s1 = dot1(s1, hvv[i], wreg3[1][ii]);
          s2 = dot1(s2, hvv[i], wreg3[2][ii]);
          s3 = dot1(s3, hvv[i], wlv[i]);
        }
      }
      s0 += __shfl_xor(s0, 1, 64);
      s1 += __shfl_xor(s1, 1, 64);
      s2 += __shfl_xor(s2, 1, 64);
      s3 += __shfl_xor(s3, 1, 64);
      if (hs == 0) { GF[R0] = s0;       GF[R0 + 256] = s1; }
      else         { GF[R0 + 512] = s2; GF[768 + R0] = s3; }
      __syncthreads();
      if (t < 256) {
        float xv = XROW[tt];
        float gi = GF[t]       + PREB[t]       + xv * PREWf[t];
        float gf = GF[256 + t] + PREB[256 + t] + xv * PREWf[256 + t];
        float gg = GF[512 + t] + PREB[512 + t] + xv * PREWf[512 + t];
        float go = GF[768 + t] + PREB[768 + t] + xv * PREWf[768 + t];
        float cn = sigm(gf) * cc + sigm(gi) * ftanh(gg);
        float hn = sigm(go) * ftanh(cn);
        cc = cn;
        ((unsigned short*)H16)[t] = f2h_u(hn);
        if (st == 1023) ws[ECL0 + d * 16384 + b * 256 + t] = cn;
      }
      __syncthreads();
      if (t < 128) y0w[(size_t)tt * 16384 + (size_t)b * 256 + d * 128 + t] = H16[t];
    }
  }
  gbar(ctrs, ++genF);   // y0 / ECL0 visible

  // ============================ E1 prep ====================================
  {
    {
      // transposed fp16 Wih1 -> ws (all 256 WGs, coalesced)
      int idx = w * 512 + t;             // 131072 uint4 total
      int dd = idx >> 16, rem = idx & 65535;
      int kc = rem >> 10, row = rem & 1023;
      WIH1Tu4[idx] = ldw8(p.eWih1, (size_t)dd * 524288 + (size_t)row * 512 + kc * 8, bfm);
    }
    if (enc_act) {
      const void* whh1 = bfm ? (const void*)((const unsigned short*)p.eWhh1 + (size_t)d * 262144)
                             : (const void*)((const float*)p.eWhh1 + (size_t)d * 262144);
#pragma unroll
      for (int sl = 0; sl < 3; ++sl)
#pragma unroll
        for (int kk = 0; kk < 16; ++kk)
          wreg3[sl][kk] = ldw8(whh1, (size_t)(R0 + sl * 256) * 256 + (size_t)hs * 128 + kk * 8, bfm);
#pragma unroll
      for (int i = 0; i < 16; ++i) {
        int idx = t + i * 512;
        int row = idx >> 5, j = idx & 31;
        WLDSu4[row * 32 + (j ^ (row & 7))] =
            ldw8(whh1, (size_t)(768 + row) * 256 + j * 8, bfm);
      }
#pragma unroll
      for (int q = 0; q < 2; ++q)
        PREB[t + q * 512] = ldin(p.eB1, d * 1024 + t + q * 512, bfm);
      if (t < 128) H16[t] = 0u;
    }
  }
  gbar(ctrs, ++genF);   // W' + y0 + flags visible

  // ====================== E1: consumers + producers ========================
  if (enc_act) {
    // -------- consumer: 1024 recurrent steps; GW arrives from producer -----
    float cc = 0.f;
    const uint4* wl = WLDSu4 + R0 * 32;
    for (int st = 0; st < 1024; ++st) {
      const int win = st >> 3, sl = st & 7;
      if (sl == 0) {
        if (t == 0) {
          while (__hip_atomic_load(&flg[w * 64], __ATOMIC_RELAXED,
                                   __HIP_MEMORY_SCOPE_AGENT) < (unsigned)(win + 1)) {
            __builtin_amdgcn_s_sleep(1);
          }
        }
        __atomic_signal_fence(__ATOMIC_ACQUIRE);
        __syncthreads();
      }
      unsigned g0 = 0, g1 = 0;
      if (t < 256) {     // issue GW loads early; consumed in the cell
        const unsigned gb = (unsigned)w * 8192 + (unsigned)(win & 1) * 4096 + (unsigned)sl * 512;
        g0 = __hip_atomic_load(&GWu[gb + t],       __ATOMIC_RELAXED, __HIP_MEMORY_SCOPE_AGENT);
        g1 = __hip_atomic_load(&GWu[gb + 256 + t], __ATOMIC_RELAXED, __HIP_MEMORY_SCOPE_AGENT);
      }
      float s0 = 0.f, s1 = 0.f, s2 = 0.f, s3 = 0.f;
#pragma unroll
      for (int hb = 0; hb < 2; ++hb) {
        uint4 wlv[8], hvv[8];
#pragma unroll
        for (int i = 0; i < 8; ++i) {
          int ii = hb * 8 + i;
          wlv[i] = wl[(hs * 16 + ii) ^ swz];
          hvv[i] = *(const uint4*)(H16 + hs * 64 + ii * 4);
        }
#pragma unroll
        for (int i = 0; i < 8; ++i) {
          int ii = hb * 8 + i;
          s0 = dot1(s0, hvv[i], wreg3[0][ii]);
          s1 = dot1(s1, hvv[i], wreg3[1][ii]);
          s2 = dot1(s2, hvv[i], wreg3[2][ii]);
          s3 = dot1(s3, hvv[i], wlv[i]);
        }
      }
      s0 += __shfl_xor(s0, 1, 64);
      s1 += __shfl_xor(s1, 1, 64);
      s2 += __shfl_xor(s2, 1, 64);
      s3 += __shfl_xor(s3, 1, 64);
      if (hs == 0) { GF[R0] = s0;       GF[R0 + 256] = s1; }
      else         { GF[R0 + 512] = s2; GF[768 + R0] = s3; }
      __syncthreads();
      if (t < 256) {
        float gi = GF[t]       + PREB[t]       + hf2f((unsigned short)(g0 & 0xffffu));
        float gf = GF[256 + t] + PREB[256 + t] + hf2f((unsigned short)(g1 & 0xffffu));
        float gg = GF[512 + t] + PREB[512 + t] + hf2f((unsigned short)(g0 >> 16));
        float go = GF[768 + t] + PREB[768 + t] + hf2f((unsigned short)(g1 >> 16));
        float cn = sigm(gf) * cc + sigm(gi) * ftanh(gg);
        float hn = sigm(go) * ftanh(cn);
        cc = cn;
        ((unsigned short*)H16)[t] = f2h_u(hn);
        if (st == 1023) ws[ECL1 + d * 16384 + b * 256 + t] = cn;
      }
      __syncthreads();
      if (st == 1023 && t < 128) EHL1u[d * 8192 + b * 128 + t] = H16[t];
      if (sl == 7 && t == 0)
        __hip_atomic_store(&flg[w * 64 + 32], (unsigned)(win + 1),
                           __ATOMIC_RELAXED, __HIP_MEMORY_SCOPE_AGENT);
    }
  } else {
    // -------- producer: GW = y0 @ Wih1^T, window-by-window -----------------
    const int chain = w - 128, dp = chain >> 6, bp = chain & 63;
    const uint4* Wt = WIH1Tu4 + (size_t)dp * 65536;
    uint4* YWu4 = (uint4*)smem;          // [8][64] uint4 (8 KB; WLDS unused here)
    for (int win = 0; win < 128; ++win) {
      if (win >= 2) {                    // ring slot reuse pacing
        if (t == 0) {
          while (__hip_atomic_load(&flg[chain * 64 + 32], __ATOMIC_RELAXED,
                                   __HIP_MEMORY_SCOPE_AGENT) < (unsigned)(win - 1)) {
            __builtin_amdgcn_s_sleep(1);
          }
        }
        __syncthreads();
      }
      {  // stage y0 window (8 steps x 64 uint4)
        int s = t >> 6, kcc = t & 63;
        int tw = dp ? (1023 - (win * 8 + s)) : (win * 8 + s);
        YWu4[s * 64 + kcc] =
            *(const uint4*)(y0w + (size_t)tw * 16384 + (size_t)bp * 256 + kcc * 4);
      }
      __syncthreads();
      float a0[8], a1[8];
#pragma unroll
      for (int s = 0; s < 8; ++s) { a0[s] = 0.f; a1[s] = 0.f; }
      for (int kc = 0; kc < 64; ++kc) {
        uint4 w0 = Wt[kc * 1024 + t];
        uint4 w1 = Wt[kc * 1024 + 512 + t];
#pragma unroll
        for (int s = 0; s < 8; ++s) {
          uint4 yv = YWu4[s * 64 + kc];
          a0[s] = dot1(a0[s], yv, w0);
          a1[s] = dot1(a1[s], yv, w1);
        }
      }
      const unsigned gb = (unsigned)chain * 8192 + (unsigned)(win & 1) * 4096;
#pragma unroll
      for (int s = 0; s < 8; ++s) {
        unsigned pw = (unsigned)f2h_u(a0[s]) | ((unsigned)f2h_u(a1[s]) << 16);
        __hip_atomic_store(&GWu[gb + s * 512 + t], pw,
                           __ATOMIC_RELAXED, __HIP_MEMORY_SCOPE_AGENT);
      }
      __syncthreads();                   // drains vmcnt: sc1 stores at IC
      if (t == 0)
        __hip_atomic_store(&flg[chain * 64], (unsigned)(win + 1),
                           __ATOMIC_RELAXED, __HIP_MEMORY_SCOPE_AGENT);
    }
  }
  gbar(ctrs, ++genF);   // EHL1/ECL1 visible

  // ===================== decoder recurrent consts R ========================
  {
    unsigned* AH0 = (unsigned*)smem;
    float* part = (float*)(smem + 33792);
    const int m = w >> 6, wl6 = w & 63;
    const void* whh;
    if (bfm) whh = (m < 2) ? (const void*)((const unsigned short*)p.dWhh0 + (size_t)m * 262144)
                           : (const void*)((const unsigned short*)p.dWhh1 + (size_t)(m - 2) * 262144);
    else     whh = (m < 2) ? (const void*)((const float*)p.dWhh0 + (size_t)m * 262144)
                           : (const void*)((const float*)p.dWhh1 + (size_t)(m - 2) * 262144);
    const void* bb;
    if (bfm) bb = (m < 2) ? (const void*)((const unsigned short*)p.dB0 + m * 1024)
                          : (const void*)((const unsigned short*)p.dB1 + (m - 2) * 1024);
    else     bb = (m < 2) ? (const void*)((const float*)p.dB0 + m * 1024)
                          : (const void*)((const float*)p.dB1 + (m - 2) * 1024);
    if (m == 0)      stage_u128(AH0, y0w + (size_t)1023 * 16384, 256, 0);
    else if (m == 1) stage_u128(AH0, y0w, 256, 128);
    else             stage_u128(AH0, EHL1u + (m - 2) * 8192, 128, 0);
    __syncthreads();
    float* dst = ws + ROF + m * 65536;
    for (int pass = 0; pass < 2; ++pass) {
      const int rowbase = wl6 * 16 + pass * 8;
      uint4 wrA[2][4];
      load_w16_rows(wrA, whh, rowbase, bfm);
      float4 acc[8];
#pragma unroll
      for (int e = 0; e < 8; ++e) acc[e] = make_float4(0.f, 0.f, 0.f, 0.f);
      dot2_t4(acc, AH0, wrA);
      reduce_R(acc, part, dst, bb, rowbase, bfm);
    }
  }
  gbar(ctrs, ++genF);   // ROF visible

  // ============================ decoder prep ===============================
  {
    // transposed fp16 dWih1 -> ws (overwrites dead y0 head)
    int idx = w * 512 + t;               // 131072 uint4 total
    int dd = idx >> 16, rem = idx & 65535;
    int kc = rem >> 10, row = rem & 1023;
    DWu4[idx] = ldw8(p.dWih1, (size_t)dd * 524288 + (size_t)row * 512 + kc * 8, bfm);
  }
  float r1i = 0.f, r1f = 0.f, r1g = 0.f, r1o = 0.f, coldc = 0.f, fwc = 0.f, fcb = 0.f;
  {
    float* R0L  = (float*)smem;          // [2][1024]
    float* WI0L = (float*)(smem + 8192); // [2][1024]
    float* C0L  = (float*)(smem + 16384);// [2][256]
    if (w < 64) {
      const int bq = w;
#pragma unroll
      for (int i = 0; i < 4; ++i) {
        int r = t + i * THR;             // 0..2047
        int dz = r >> 10, rr = r & 1023;
        R0L[r]  = ws[ROF + dz * 65536 + (size_t)bq * 1024 + rr];
        WI0L[r] = ldin(p.dWih0, dz * 1024 + rr, bfm);
      }
      C0L[t >= 512 ? 0 : t] = ws[ECL0 + (t >> 8) * 16384 + (size_t)bq * 256 + (t & 255)];
      const int dd2 = t >> 8, col = t & 255;
      r1i = ws[ROF + (2 + dd2) * 65536 + (size_t)bq * 1024 +       col];
      r1f = ws[ROF + (2 + dd2) * 65536 + (size_t)bq * 1024 + 256 + col];
      r1g = ws[ROF + (2 + dd2) * 65536 + (size_t)bq * 1024 + 512 + col];
      r1o = ws[ROF + (2 + dd2) * 65536 + (size_t)bq * 1024 + 768 + col];
      coldc = ws[ECL1 + dd2 * 16384 + (size_t)bq * 256 + col];
      fwc = ldin(p.fcW, dd2 * 256 + col, bfm);
      fcb = ldin(p.fcb, 0, bfm);
    }
  }
  gbar(ctrs, ++genF);   // DW' visible

  // ===================== decoder loop: one WG per batch ====================
  if (w < 64) {
    const int bq = w;
    float* R0L  = (float*)smem;
    float* WI0L = (float*)(smem + 8192);
    float* C0L  = (float*)(smem + 16384);
    unsigned* ZV = (unsigned*)(smem + 18432);   // 256 uints = 512 fp16 z
    const int dd2 = t >> 8, col = t & 255;
    const uint4* DWt = DWu4 + (size_t)dd2 * 65536;

    // initial z from y = 0
    {
      float gi = R0L[dd2 * 1024 +       col];
      float gf = R0L[dd2 * 1024 + 256 + col];
      float gg = R0L[dd2 * 1024 + 512 + col];
      float go = R0L[dd2 * 1024 + 768 + col];
      float cold = C0L[dd2 * 256 + col];
      float cn = sigm(gf) * cold + sigm(gi) * ftanh(gg);
      float hz = sigm(go) * ftanh(cn);
      ((unsigned short*)ZV)[t] = f2h_u(hz);
    }
    __syncthreads();

    float yp1 = 3.0e38f, yp2 = -3.0e38f;
    for (int st = 0; st < 1024; ++st) {
      // l1 gates for (dd2, col): 4 rows, K=512, coalesced DW' loads
      float ai = 0.f, af = 0.f, ag = 0.f, ao = 0.f;
      for (int kc = 0; kc < 64; ++kc) {
        uint4 zv = *(const uint4*)(ZV + kc * 4);
        uint4 w0 = DWt[kc * 1024 +       col];
        uint4 w1 = DWt[kc * 1024 + 256 + col];
        uint4 w2 = DWt[kc * 1024 + 512 + col];
        uint4 w3 = DWt[kc * 1024 + 768 + col];
        ai = dot1(ai, zv, w0);
        af = dot1(af, zv, w1);
        ag = dot1(ag, zv, w2);
        ao = dot1(ao, zv, w3);
      }
      float gi = ai + r1i, gf = af + r1f, gg = ag + r1g, go = ao + r1o;
      float cn = sigm(gf) * coldc + sigm(gi) * ftanh(gg);
      float h1 = sigm(go) * ftanh(cn);
      GF[t] = h1 * fwc;
      __syncthreads();
      if (t < 64) {
        const float* q = GF + t;
        GF[t] = ((q[0] + q[64]) + (q[128] + q[192])) +
                ((q[256] + q[320]) + (q[384] + q[448]));
      }
      __syncthreads();
      if (t == 0) {
        float yy = fcb;
        for (int i = 0; i < 64; ++i) yy += GF[i];
        YL[0] = yy;
      }
      __syncthreads();
      float ynew = YL[0];
      if (t == 0) stout(p.out, (size_t)bq * 1024 + st, ynew, bfm);
      if (ynew == yp1) {               // exact fixed point
        for (int t2 = st + 1 + t; t2 < 1024; t2 += THR)
          stout(p.out, (size_t)bq * 1024 + t2, ynew, bfm);
        break;
      }
      if (ynew == yp2) {               // exact period-2 cycle
        for (int t2 = st + 1 + t; t2 < 1024; t2 += THR)
          stout(p.out, (size_t)bq * 1024 + t2, ((t2 - st) & 1) ? yp1 : ynew, bfm);
        break;
      }
      yp2 = yp1; yp1 = ynew;
      if (st < 1023) {
        __syncthreads();               // ZV fully consumed before overwrite
        float gi2 = ynew * WI0L[dd2 * 1024 +       col] + R0L[dd2 * 1024 +       col];
        float gf2 = ynew * WI0L[dd2 * 1024 + 256 + col] + R0L[dd2 * 1024 + 256 + col];
        float gg2 = ynew * WI0L[dd2 * 1024 + 512 + col] + R0L[dd2 * 1024 + 512 + col];
        float go2 = ynew * WI0L[dd2 * 1024 + 768 + col] + R0L[dd2 * 1024 + 768 + col];
        float cold = C0L[dd2 * 256 + col];
        float cn2 = sigm(gf2) * cold + sigm(gi2) * ftanh(gg2);
        float hz = sigm(go2) * ftanh(cn2);
        ((unsigned short*)ZV)[t] = f2h_u(hz);
        __syncthreads();
      }
    }
  }
}

// diagnostic: if ws too small, encode ws_size (MB) into the output signature
__global__ void fill_sig(unsigned short* out, int n, float val) {
  int i = blockIdx.x * 256 + threadIdx.x;
  __hip_bfloat16 b = __float2bfloat16(val);
  if (i < n) out[i] = *reinterpret_cast<unsigned short*>(&b);
}

extern "C" void kernel_launch(void* const* d_in, const int* in_sizes, int n_in,
                              void* d_out, int out_size, void* d_ws, size_t ws_size,
                              hipStream_t stream) {
  (void)in_sizes; (void)n_in;
  if (ws_size < WS_REQ_BYTES) {
    float sig = 2048.0f + (float)(ws_size >> 20);
    fill_sig<<<(out_size + 255) / 256, 256, 0, stream>>>(
        (unsigned short*)d_out, out_size, sig);
    return;
  }
  hipMemsetAsync(d_ws, 0, 8192, stream);  // zero barrier counters

  SeqParams p;
  p.x     = d_in[0];
  p.eWih0 = d_in[1];
  p.eWhh0 = d_in[2];
  p.eB0   = d_in[3];
  p.eWih1 = d_in[4];
  p.eWhh1 = d_in[5];
  p.eB1   = d_in[6];
  p.dWih0 = d_in[7];
  p.dWhh0 = d_in[8];
  p.dB0   = d_in[9];
  p.dWih1 = d_in[10];
  p.dWhh1 = d_in[11];
  p.dB1   = d_in[12];
  p.fcW   = d_in[13];
  p.fcb   = d_in[14];
  p.out   = d_out;
  p.ws    = (float*)d_ws;
  p.ctrs  = (unsigned*)d_ws;

  seq2seq_kernel<<<dim3(NWG), dim3(THR), 0, stream>>>(p);
}